// Round 2
// baseline (52191.028 us; speedup 1.0000x reference)
//
#include <hip/hip_runtime.h>
#include <hip/hip_bf16.h>

#define SLEN 2048
#define BROWS 64
#define IDIM 512
#define HDIM 512
#define KTOT 1024
#define NWG 32
#define NTHREADS 512

typedef __bf16 bf16x8 __attribute__((ext_vector_type(8)));
typedef float  f32x4  __attribute__((ext_vector_type(4)));
typedef int    i32x4  __attribute__((ext_vector_type(4)));

__device__ inline unsigned short f2bf(float f) {
  union { float f; unsigned u; } v; v.f = f;
  unsigned r = v.u + 0x7FFFu + ((v.u >> 16) & 1u);
  return (unsigned short)(r >> 16);
}
__device__ inline float sigm(float x) {
  return __builtin_amdgcn_rcpf(1.f + __expf(-x));
}
__device__ inline float tanh_f(float x) {
  float e = __expf(2.f * x);
  return 1.f - 2.f * __builtin_amdgcn_rcpf(e + 1.f);
}

// CT[row][k]: row = w*64 + tile*16 + nn ; tile0=[i f],1=[g o],2=[i' f'],3=[g' o']
// gate = (tile&1)*2 + (nn>>3); hcol = w*16 + (tile>>1)*8 + (nn&7); j = gate*512+hcol
// k<512: W[k][j]; k>=512: U[k-512][j]
__global__ __launch_bounds__(256) void prep_ct(const float* __restrict__ W,
                                               const float* __restrict__ U,
                                               unsigned short* __restrict__ CT) {
  int k = blockIdx.x;  // 0..1023
  const float* src = (k < IDIM) ? (W + (size_t)k * 2048) : (U + (size_t)(k - IDIM) * 2048);
  for (int j = threadIdx.x; j < 2048; j += 256) {
    int gate = j >> 9, hcol = j & 511;
    int w = hcol >> 4, hl = hcol & 15;
    int tile = ((hl >> 3) << 1) + (gate >> 1);
    int nn = ((gate & 1) << 3) + (hl & 7);
    int row = w * 64 + tile * 16 + nn;
    CT[(size_t)row * KTOT + k] = f2bf(src[j]);
  }
}

__global__ __launch_bounds__(NTHREADS) void lstm_persist(
    const float* __restrict__ x, const float* __restrict__ bias,
    const unsigned short* __restrict__ CT,
    unsigned short* __restrict__ hbuf,   // [2][64][512] bf16
    unsigned* __restrict__ flags,
    float* __restrict__ out) {
  const int w    = blockIdx.x;        // 0..31, owns H-cols [16w,16w+16)
  const int tid  = threadIdx.x;
  const int lane = tid & 63;
  const int wid  = tid >> 6;          // 0..7
  const int lg   = lane >> 4;         // 0..3
  const int lc   = lane & 15;
  const bool isrec = wid < 4;
  const int wv = isrec ? wid : wid - 4;  // 0..3
  const int r  = wv >> 1;                // row half
  const int n  = wv & 1;                 // col half (tiles 2n,2n+1)

  __shared__ unsigned short Ulds[32768];     // [64 cols][512 k] bf16, XOR-swizzled
  __shared__ f32x4 ring[2][4][2][2][64];     // [slot][wv][m][nt][lane]

  // ---- cooperative U -> LDS (swizzled: lin ^ (((lin>>10)&7)<<4)) ----
  #pragma unroll
  for (int i = 0; i < 8; ++i) {
    int idx16 = tid + NTHREADS * i;          // 16B chunk id, 4096 total
    int row = idx16 >> 6;                    // U-col 0..63
    int cir = idx16 & 63;
    i32x4 v = *(const i32x4*)(CT + (size_t)(w * 64 + row) * KTOT + 512 + cir * 8);
    int lin = idx16 * 16;
    *(i32x4*)((char*)Ulds + (lin ^ (((lin >> 10) & 7) << 4))) = v;
  }

  // ---- producer-wave invariants ----
  bf16x8 Wf[2][16];
  float bias_v[2] = {0.f, 0.f};
  if (!isrec) {
    #pragma unroll
    for (int nt = 0; nt < 2; ++nt) {
      #pragma unroll
      for (int kk = 0; kk < 16; ++kk)
        Wf[nt][kk] = *(const bf16x8*)(CT + (size_t)(w * 64 + (2 * n + nt) * 16 + lc) * KTOT
                                      + kk * 32 + lg * 8);
      int tile = 2 * n + nt;
      int gate = ((tile & 1) << 1) + (lc >> 3);
      int hcol = w * 16 + ((tile >> 1) << 3) + (lc & 7);
      bias_v[nt] = bias[gate * HDIM + hcol];
    }
  }

  auto PROD = [&](int tt, int slot) {   // xW[tt] + bias -> ring[slot]
    f32x4 pa[2][2];
    #pragma unroll
    for (int m = 0; m < 2; ++m)
      #pragma unroll
      for (int nt = 0; nt < 2; ++nt)
        pa[m][nt] = (f32x4){bias_v[nt], bias_v[nt], bias_v[nt], bias_v[nt]};
    #pragma unroll
    for (int kk = 0; kk < 16; ++kk) {
      bf16x8 af[2];
      #pragma unroll
      for (int m = 0; m < 2; ++m) {
        const float* xp = x + ((size_t)tt * BROWS + 32 * r + 16 * m + lc) * IDIM
                        + kk * 32 + lg * 8;
        f32x4 v0 = *(const f32x4*)xp;
        f32x4 v1 = *(const f32x4*)(xp + 4);
        bf16x8 a;
        #pragma unroll
        for (int j = 0; j < 4; ++j) { a[j] = (__bf16)v0[j]; a[4 + j] = (__bf16)v1[j]; }
        af[m] = a;
      }
      pa[0][0] = __builtin_amdgcn_mfma_f32_16x16x32_bf16(af[0], Wf[0][kk], pa[0][0], 0, 0, 0);
      pa[0][1] = __builtin_amdgcn_mfma_f32_16x16x32_bf16(af[0], Wf[1][kk], pa[0][1], 0, 0, 0);
      pa[1][0] = __builtin_amdgcn_mfma_f32_16x16x32_bf16(af[1], Wf[0][kk], pa[1][0], 0, 0, 0);
      pa[1][1] = __builtin_amdgcn_mfma_f32_16x16x32_bf16(af[1], Wf[1][kk], pa[1][1], 0, 0, 0);
    }
    #pragma unroll
    for (int m = 0; m < 2; ++m)
      #pragma unroll
      for (int nt = 0; nt < 2; ++nt)
        ring[slot][wv][m][nt][lane] = pa[m][nt];
  };

  if (!isrec) PROD(0, 0);
  __syncthreads();

  float cst[4] = {0.f, 0.f, 0.f, 0.f};
  const int  mcol = w * 16 + 8 * n + (lc & 7);
  const bool hi = lc >= 8;
  const size_t HS = (size_t)SLEN * BROWS * HDIM;

  for (int t = 0; t < SLEN; ++t) {
    if (isrec) {
      f32x4 acc[2][2];
      #pragma unroll
      for (int m = 0; m < 2; ++m)
        #pragma unroll
        for (int nt = 0; nt < 2; ++nt)
          acc[m][nt] = ring[t & 1][wv][m][nt][lane];

      if (t > 0) {
        const unsigned short* hb = hbuf + (size_t)(t & 1) * BROWS * HDIM;
        i32x4 A[2][16];
        #pragma unroll
        for (int kk = 0; kk < 16; ++kk)
          #pragma unroll
          for (int m = 0; m < 2; ++m) {
            const unsigned short* p = hb + (size_t)(32 * r + 16 * m + lc) * HDIM
                                    + kk * 32 + lg * 8;
            asm volatile("global_load_dwordx4 %0, %1, off sc0 sc1"
                         : "=v"(A[m][kk]) : "v"(p));
          }
        asm volatile("s_waitcnt vmcnt(0)" ::: "memory");
        __builtin_amdgcn_sched_barrier(0);
        #pragma unroll
        for (int kk = 0; kk < 16; ++kk) {
          int koff = (kk * 32 + lg * 8) * 2;
          int l0 = ((2 * n + 0) * 16 + lc) * 1024 + koff;
          int l1 = ((2 * n + 1) * 16 + lc) * 1024 + koff;
          bf16x8 b0 = *(const bf16x8*)((char*)Ulds + (l0 ^ (((l0 >> 10) & 7) << 4)));
          bf16x8 b1 = *(const bf16x8*)((char*)Ulds + (l1 ^ (((l1 >> 10) & 7) << 4)));
          union { i32x4 i; bf16x8 h; } u0, u1;
          u0.i = A[0][kk]; u1.i = A[1][kk];
          acc[0][0] = __builtin_amdgcn_mfma_f32_16x16x32_bf16(u0.h, b0, acc[0][0], 0, 0, 0);
          acc[0][1] = __builtin_amdgcn_mfma_f32_16x16x32_bf16(u0.h, b1, acc[0][1], 0, 0, 0);
          acc[1][0] = __builtin_amdgcn_mfma_f32_16x16x32_bf16(u1.h, b0, acc[1][0], 0, 0, 0);
          acc[1][1] = __builtin_amdgcn_mfma_f32_16x16x32_bf16(u1.h, b1, acc[1][1], 0, 0, 0);
        }
      }

      // ---- epilogue ----
      unsigned short* hnx = hbuf + (size_t)((t + 1) & 1) * BROWS * HDIM;
      #pragma unroll
      for (int reg = 0; reg < 4; ++reg) {
        float a00 = acc[0][0][reg], a01 = acc[0][1][reg];
        float a10 = acc[1][0][reg], a11 = acc[1][1][reg];
        float e00 = __shfl_xor(a00, 8, 64);
        float e01 = __shfl_xor(a01, 8, 64);
        float e10 = __shfl_xor(a10, 8, 64);
        float e11 = __shfl_xor(a11, 8, 64);
        float gi = hi ? e10 : a00;
        float gf = hi ? a10 : e00;
        float gg = hi ? e11 : a01;
        float go = hi ? a11 : e01;
        float it = sigm(gi), ft = sigm(gf), gt = tanh_f(gg), ot = sigm(go);
        float cn = ft * cst[reg] + it * gt;
        cst[reg] = cn;
        float hn = ot * tanh_f(cn);
        int b = 32 * r + (hi ? 16 : 0) + 4 * lg + reg;
        out[(size_t)t * (BROWS * HDIM) + (size_t)b * HDIM + mcol] = hn;
        unsigned short hv = f2bf(hn);
        const unsigned short* hp = hnx + (size_t)b * HDIM + mcol;
        asm volatile("global_store_short %0, %1, off sc0 sc1"
                     :: "v"(hp), "v"(hv) : "memory");
        if (t == SLEN - 1) {
          out[HS + (size_t)b * HDIM + mcol] = hn;
          out[HS + BROWS * HDIM + (size_t)b * HDIM + mcol] = cn;
        }
      }
    } else if (t + 1 < SLEN) {
      PROD(t + 1, (t + 1) & 1);
    }

    if (t + 1 < SLEN) {
      asm volatile("s_waitcnt vmcnt(0)" ::: "memory");
      __syncthreads();
      if (wid == 0) {
        unsigned gen = (unsigned)(t + 1);
        if (lane == 0)
          __hip_atomic_store(flags + (size_t)w * 32, gen, __ATOMIC_RELAXED,
                             __HIP_MEMORY_SCOPE_AGENT);
        if (lane < NWG) {
          unsigned v;
          do {
            v = __hip_atomic_load(flags + (size_t)lane * 32, __ATOMIC_RELAXED,
                                  __HIP_MEMORY_SCOPE_AGENT);
          } while (v < gen);
        }
      }
      __syncthreads();
    }
  }
}

extern "C" void kernel_launch(void* const* d_in, const int* in_sizes, int n_in,
                              void* d_out, int out_size, void* d_ws, size_t ws_size,
                              hipStream_t stream) {
  const float* x    = (const float*)d_in[0];
  const float* W    = (const float*)d_in[1];
  const float* U    = (const float*)d_in[2];
  const float* bias = (const float*)d_in[3];
  float* out = (float*)d_out;

  unsigned short* CT   = (unsigned short*)d_ws;                                   // 4 MiB
  unsigned short* hbuf = (unsigned short*)((char*)d_ws + (size_t)2048 * KTOT * 2);// 128 KiB
  unsigned* flags = (unsigned*)((char*)d_ws + (size_t)2048 * KTOT * 2
                                            + (size_t)2 * BROWS * HDIM * 2);      // 4 KiB

  hipMemsetAsync(flags, 0, NWG * 32 * sizeof(unsigned), stream);
  prep_ct<<<KTOT, 256, 0, stream>>>(W, U, CT);
  lstm_persist<<<NWG, NTHREADS, 0, stream>>>(x, bias, CT, hbuf, flags, out);
}

// Round 3
// 19502.676 us; speedup vs baseline: 2.6761x; 2.6761x over previous
//
#include <hip/hip_runtime.h>
#include <hip/hip_bf16.h>

#define SLEN 2048
#define BROWS 64
#define IDIM 512
#define HDIM 512
#define NGROUP 4      // row groups (16 batch rows each)
#define GW 16         // col-split WGs per group
#define NWG 64
#define NTHREADS 512

typedef __bf16 bf16x8 __attribute__((ext_vector_type(8)));
typedef float  f32x4  __attribute__((ext_vector_type(4)));
typedef int    i32x4  __attribute__((ext_vector_type(4)));

__device__ inline unsigned short f2bf(float f) {
  union { float f; unsigned u; } v; v.f = f;
  unsigned r = v.u + 0x7FFFu + ((v.u >> 16) & 1u);
  return (unsigned short)(r >> 16);
}
__device__ inline float sigm(float x) {
  return __builtin_amdgcn_rcpf(1.f + __expf(-x));
}
__device__ inline float tanh_f(float x) {
  float e = __expf(2.f * x);
  return 1.f - 2.f * __builtin_amdgcn_rcpf(e + 1.f);
}

// CT[row][k], row-major K=1024. row encodes (w, p, nt, nn):
//   j = gate*512 + hcol ; gate = nt*2 + (nn>>3) ; hcol = w*32 + p*8 + (nn&7)
//   row = w*128 + p*32 + nt*16 + nn
// k < 512: W[k][j] ; k >= 512: U[k-512][j]
__global__ __launch_bounds__(256) void prep_ct(const float* __restrict__ W,
                                               const float* __restrict__ U,
                                               unsigned short* __restrict__ CT) {
  int k = blockIdx.x;  // 0..1023
  const float* src = (k < IDIM) ? (W + (size_t)k * 2048) : (U + (size_t)(k - IDIM) * 2048);
  for (int j = threadIdx.x; j < 2048; j += 256) {
    int gate = j >> 9, hcol = j & 511;
    int w = hcol >> 5, p = (hcol >> 3) & 3, sub = hcol & 7;
    int nt = gate >> 1, nn = ((gate & 1) << 3) | sub;
    int row = w * 128 + p * 32 + nt * 16 + nn;
    CT[(size_t)row * 1024 + k] = f2bf(src[j]);
  }
}

__global__ __launch_bounds__(NTHREADS, 2) void lstm_persist(
    const float* __restrict__ x, const float* __restrict__ bias,
    const unsigned short* __restrict__ CT,
    unsigned short* __restrict__ hG,    // [2][64][512] bf16 exchange buffers
    unsigned* __restrict__ flags,       // [NGROUP][GW]
    float* __restrict__ out) {
  const int bid  = blockIdx.x;
  const int g    = bid & 3;            // row group: batch rows [16g, 16g+16)
  const int w    = bid >> 2;           // col split: hcols [32w, 32w+32)
  const int tid  = threadIdx.x;
  const int lane = tid & 63;
  const int wid  = tid >> 6;           // 0..7
  const int lg   = lane >> 4;          // 0..3
  const int lc   = lane & 15;
  const bool isrec = wid < 4;
  const int p    = isrec ? wid : wid - 4;  // wave's col sub-block: hcols w*32+p*8..+8

  __shared__ unsigned short hstage[16 * 512];   // h(t), XOR-swizzled rows, 16KB
  __shared__ unsigned short slice[16 * 32];     // this WG's h slice, 1KB
  __shared__ f32x4 ring[2][4][2][64];           // xW+bias handoff, 16KB

  // ---- step-invariant weight fragments, fully register-resident ----
  // rec waves: U-part (k 512..1024); prod waves: W-part (k 0..512)
  bf16x8 Bf[2][16];
  {
    const int koff = isrec ? 512 : 0;
    const size_t rbase = (size_t)(w * 128 + p * 32) * 1024;
    #pragma unroll
    for (int nt = 0; nt < 2; ++nt)
      #pragma unroll
      for (int kk = 0; kk < 16; ++kk)
        Bf[nt][kk] = *(const bf16x8*)(CT + rbase + (size_t)(nt * 16 + lc) * 1024
                                      + koff + kk * 32 + lg * 8);
  }
  float bias_v[2];
  #pragma unroll
  for (int nt = 0; nt < 2; ++nt) {
    int gate = nt * 2 + (lc >> 3);
    int hcol = w * 32 + p * 8 + (lc & 7);
    bias_v[nt] = bias[gate * HDIM + hcol];
  }

  const float* xbase = x + ((size_t)16 * g + lc) * IDIM + lg * 8;

  // producer: gates_x(tt) = x[tt]@W + bias -> ring[slot]
  auto PROD = [&](int tt, int slot) {
    f32x4 pa0 = {bias_v[0], bias_v[0], bias_v[0], bias_v[0]};
    f32x4 pa1 = {bias_v[1], bias_v[1], bias_v[1], bias_v[1]};
    const float* xp = xbase + (size_t)tt * (BROWS * IDIM);
    #pragma unroll
    for (int kk = 0; kk < 16; ++kk) {
      f32x4 v0 = *(const f32x4*)(xp + kk * 32);
      f32x4 v1 = *(const f32x4*)(xp + kk * 32 + 4);
      bf16x8 a;
      #pragma unroll
      for (int j = 0; j < 4; ++j) { a[j] = (__bf16)v0[j]; a[4 + j] = (__bf16)v1[j]; }
      pa0 = __builtin_amdgcn_mfma_f32_16x16x32_bf16(a, Bf[0][kk], pa0, 0, 0, 0);
      pa1 = __builtin_amdgcn_mfma_f32_16x16x32_bf16(a, Bf[1][kk], pa1, 0, 0, 0);
    }
    ring[slot][p][0][lane] = pa0;
    ring[slot][p][1][lane] = pa1;
  };

  if (!isrec) PROD(0, 0);
  __syncthreads();

  float cst[4] = {0.f, 0.f, 0.f, 0.f};
  const bool lo = (lc < 8);
  const int hcol = w * 32 + p * 8 + (lc & 7);
  const int sw = (lc & 7) << 4;
  const size_t HS = (size_t)SLEN * BROWS * HDIM;

  for (int t = 0; t < SLEN; ++t) {
    if (isrec) {
      f32x4 acc0 = ring[t & 1][p][0][lane];
      f32x4 acc1 = ring[t & 1][p][1][lane];
      if (t > 0) {
        #pragma unroll
        for (int kk = 0; kk < 16; ++kk) {
          int byteoff = lc * 1024 + (((kk * 32 + lg * 8) * 2) ^ sw);
          bf16x8 a = *(const bf16x8*)((const char*)hstage + byteoff);
          acc0 = __builtin_amdgcn_mfma_f32_16x16x32_bf16(a, Bf[0][kk], acc0, 0, 0, 0);
          acc1 = __builtin_amdgcn_mfma_f32_16x16x32_bf16(a, Bf[1][kk], acc1, 0, 0, 0);
        }
      }
      // epilogue: lane lo holds i(acc0), g(acc1); partners hold f, o
      #pragma unroll
      for (int reg = 0; reg < 4; ++reg) {
        float gi = acc0[reg];
        float gf = __shfl_xor(acc0[reg], 8, 64);
        float gg = acc1[reg];
        float go = __shfl_xor(acc1[reg], 8, 64);
        float it = sigm(gi), ft = sigm(gf), gt = tanh_f(gg), ot = sigm(go);
        float cn = ft * cst[reg] + it * gt;
        cst[reg] = cn;
        float hn = ot * tanh_f(cn);
        if (lo) {
          int bl = 4 * lg + reg;              // local batch row
          size_t bglob = (size_t)16 * g + bl;
          out[(size_t)t * (BROWS * HDIM) + bglob * HDIM + hcol] = hn;
          slice[bl * 32 + p * 8 + (lc & 7)] = f2bf(hn);
          if (t == SLEN - 1) {
            out[HS + bglob * HDIM + hcol] = hn;
            out[HS + BROWS * HDIM + bglob * HDIM + hcol] = cn;
          }
        }
      }
    } else if (t + 1 < SLEN) {
      PROD(t + 1, (t + 1) & 1);
    }

    if (t + 1 < SLEN) {
      __syncthreads();   // slice + ring complete

      const size_t bufoff = (size_t)((t + 1) & 1) * BROWS * HDIM;
      if (wid == 0) {
        // one wave pushes the WG's 1KB slice as 16 full 64B lines
        int r = lane >> 2, c = lane & 3;
        i32x4 v = *(const i32x4*)((const char*)slice + r * 64 + c * 16);
        const unsigned short* sp = hG + bufoff + ((size_t)16 * g + r) * HDIM
                                 + w * 32 + c * 8;
        asm volatile("global_store_dwordx4 %0, %1, off sc0 sc1"
                     :: "v"(sp), "v"(v) : "memory");
        asm volatile("s_waitcnt vmcnt(0)" ::: "memory");
        if (lane == 0)
          __hip_atomic_store(flags + g * GW + w, (unsigned)(t + 1),
                             __ATOMIC_RELAXED, __HIP_MEMORY_SCOPE_AGENT);
        if (lane < GW) {
          unsigned v2;
          do {
            v2 = __hip_atomic_load(flags + g * GW + lane, __ATOMIC_RELAXED,
                                   __HIP_MEMORY_SCOPE_AGENT);
          } while (v2 < (unsigned)(t + 1));
        }
      }
      __syncthreads();   // barrier passed

      // cooperative load of full group h(t+1): 16KB, 32B/thread
      {
        const unsigned short* gp = hG + bufoff + (size_t)16 * g * HDIM + tid * 16;
        i32x4 v0, v1;
        asm volatile("global_load_dwordx4 %0, %1, off sc0 sc1" : "=v"(v0) : "v"(gp));
        asm volatile("global_load_dwordx4 %0, %1, off sc0 sc1" : "=v"(v1) : "v"(gp + 8));
        asm volatile("s_waitcnt vmcnt(0)" ::: "memory");
        int row = tid >> 5;
        int colb0 = (tid & 31) * 32;
        int rsw = (row & 7) << 4;
        *(i32x4*)((char*)hstage + row * 1024 + (colb0 ^ rsw)) = v0;
        *(i32x4*)((char*)hstage + row * 1024 + ((colb0 + 16) ^ rsw)) = v1;
      }
      __syncthreads();   // hstage ready for step t+1
    }
  }
}

extern "C" void kernel_launch(void* const* d_in, const int* in_sizes, int n_in,
                              void* d_out, int out_size, void* d_ws, size_t ws_size,
                              hipStream_t stream) {
  const float* x    = (const float*)d_in[0];
  const float* W    = (const float*)d_in[1];
  const float* U    = (const float*)d_in[2];
  const float* bias = (const float*)d_in[3];
  float* out = (float*)d_out;

  unsigned short* CT = (unsigned short*)d_ws;                                    // 4 MiB
  unsigned short* hG = (unsigned short*)((char*)d_ws + (size_t)2048 * 1024 * 2); // 128 KiB
  unsigned* flags = (unsigned*)((char*)d_ws + (size_t)2048 * 1024 * 2
                                            + (size_t)2 * BROWS * HDIM * 2);     // 256 B

  hipMemsetAsync(flags, 0, NGROUP * GW * sizeof(unsigned), stream);
  prep_ct<<<1024, 256, 0, stream>>>(W, U, CT);
  lstm_persist<<<NWG, NTHREADS, 0, stream>>>(x, bias, CT, hG, flags, out);
}

// Round 5
// 18562.997 us; speedup vs baseline: 2.8116x; 1.0506x over previous
//
#include <hip/hip_runtime.h>
#include <hip/hip_bf16.h>

#define SLEN 2048
#define BROWS 64
#define IDIM 512
#define HDIM 512
#define NGROUP 4
#define GW 16
#define NWG 64
#define NTHREADS 512

typedef __bf16 bf16x8 __attribute__((ext_vector_type(8)));
typedef float  f32x4  __attribute__((ext_vector_type(4)));
typedef int    i32x4  __attribute__((ext_vector_type(4)));

__device__ inline unsigned short f2bf(float f) {
  union { float f; unsigned u; } v; v.f = f;
  unsigned r = v.u + 0x7FFFu + ((v.u >> 16) & 1u);
  return (unsigned short)(r >> 16);
}
__device__ inline float sigm(float x) {
  return __builtin_amdgcn_rcpf(1.f + __expf(-x));
}
__device__ inline float tanh_f(float x) {
  float e = __expf(2.f * x);
  return 1.f - 2.f * __builtin_amdgcn_rcpf(e + 1.f);
}

// CT[row][k], row-major K=1024. row = w*128 + p*32 + nt*16 + nn
//   j = gate*512 + hcol ; gate = nt*2 + (nn>>3) ; hcol = w*32 + p*8 + (nn&7)
__global__ __launch_bounds__(256) void prep_ct(const float* __restrict__ W,
                                               const float* __restrict__ U,
                                               unsigned short* __restrict__ CT) {
  int k = blockIdx.x;
  const float* src = (k < IDIM) ? (W + (size_t)k * 2048) : (U + (size_t)(k - IDIM) * 2048);
  for (int j = threadIdx.x; j < 2048; j += 256) {
    int gate = j >> 9, hcol = j & 511;
    int w = hcol >> 5, p = (hcol >> 3) & 3, sub = hcol & 7;
    int nt = gate >> 1, nn = ((gate & 1) << 3) | sub;
    int row = w * 128 + p * 32 + nt * 16 + nn;
    CT[(size_t)row * 1024 + k] = f2bf(src[j]);
  }
}

__global__ __launch_bounds__(NTHREADS, 2) void lstm_persist(
    const float* __restrict__ x, const float* __restrict__ bias,
    const unsigned short* __restrict__ CT,
    unsigned short* __restrict__ hG,    // [2][64][512] bf16
    unsigned* __restrict__ flags,       // [NGROUP*GW] on 64B stride
    float* __restrict__ out) {
  const int bid  = blockIdx.x;
  const int g    = bid & 3;
  const int w    = bid >> 2;
  const int tid  = threadIdx.x;
  const int lane = tid & 63;
  const int wid  = tid >> 6;
  const int lg   = lane >> 4;
  const int lc   = lane & 15;
  const bool isrec = wid < 4;
  const int p = isrec ? wid : wid - 4;

  __shared__ f32x4 ring[2][4][2][64];
  __shared__ int gsync;

  if (tid == 0) gsync = 0;

  // ---- step-invariant weights: rec waves U-half, prod waves W-half ----
  i32x4 Bf0[16], Bf1[16];
  {
    const int koff = isrec ? 512 : 0;
    const unsigned short* ctb = CT + (size_t)(w * 128 + p * 32) * 1024 + koff;
    #pragma unroll
    for (int kk = 0; kk < 16; ++kk) {
      Bf0[kk] = *(const i32x4*)(ctb + (size_t)lc * 1024 + kk * 32 + lg * 8);
      Bf1[kk] = *(const i32x4*)(ctb + (size_t)(16 + lc) * 1024 + kk * 32 + lg * 8);
    }
  }
  #pragma unroll
  for (int kk = 0; kk < 16; ++kk) {
    asm volatile("" : "+v"(Bf0[kk]));
    asm volatile("" : "+v"(Bf1[kk]));
  }

  float bias_v[2];
  #pragma unroll
  for (int nt = 0; nt < 2; ++nt) {
    int gate = nt * 2 + (lc >> 3);
    int hcol = w * 32 + p * 8 + (lc & 7);
    bias_v[nt] = bias[gate * HDIM + hcol];
  }

  const float* xbase = x + ((size_t)16 * g + lc) * IDIM + lg * 8;

  auto PROD = [&](int tt, int slot) {
    f32x4 pa0 = {bias_v[0], bias_v[0], bias_v[0], bias_v[0]};
    f32x4 pa1 = {bias_v[1], bias_v[1], bias_v[1], bias_v[1]};
    const float* xp = xbase + (size_t)tt * (BROWS * IDIM);
    #pragma unroll
    for (int kk = 0; kk < 16; ++kk) {
      f32x4 v0 = *(const f32x4*)(xp + kk * 32);
      f32x4 v1 = *(const f32x4*)(xp + kk * 32 + 4);
      bf16x8 a;
      #pragma unroll
      for (int j = 0; j < 4; ++j) { a[j] = (__bf16)v0[j]; a[4 + j] = (__bf16)v1[j]; }
      union { i32x4 i; bf16x8 h; } u0, u1;
      u0.i = Bf0[kk]; u1.i = Bf1[kk];
      pa0 = __builtin_amdgcn_mfma_f32_16x16x32_bf16(a, u0.h, pa0, 0, 0, 0);
      pa1 = __builtin_amdgcn_mfma_f32_16x16x32_bf16(a, u1.h, pa1, 0, 0, 0);
    }
    ring[slot][p][0][lane] = pa0;
    ring[slot][p][1][lane] = pa1;
  };

  if (!isrec) PROD(0, 0);
  __syncthreads();

  float cst[4] = {0.f, 0.f, 0.f, 0.f};
  const bool lo = (lc < 8);
  const int hcol = w * 32 + p * 8 + (lc & 7);
  const size_t HS = (size_t)SLEN * BROWS * HDIM;
  const unsigned short* ap0 = hG + ((size_t)16 * g + lc) * HDIM + lg * 8;
  const unsigned short* ap1 = ap0 + (size_t)BROWS * HDIM;

  for (int t = 0; t < SLEN; ++t) {
    if (isrec) {
      f32x4 acc0 = ring[t & 1][p][0][lane];
      f32x4 acc1 = ring[t & 1][p][1][lane];

      if (t > 0) {
        // wave 0 polls the 16 peer flags; waves 1-3 ds-spin on gsync
        if (wid == 0) {
          if (lane < GW) {
            const unsigned* fp = flags + (size_t)(g * GW + lane) * 16;
            while (__hip_atomic_load(fp, __ATOMIC_RELAXED,
                                     __HIP_MEMORY_SCOPE_AGENT) < (unsigned)t)
              __builtin_amdgcn_s_sleep(1);
          }
          if (lane == 0)
            __hip_atomic_store(&gsync, t, __ATOMIC_RELEASE,
                               __HIP_MEMORY_SCOPE_WORKGROUP);
        } else {
          while (__hip_atomic_load(&gsync, __ATOMIC_ACQUIRE,
                                   __HIP_MEMORY_SCOPE_WORKGROUP) < t)
            __builtin_amdgcn_s_sleep(1);
        }

        // load h(t) A-fragments direct to registers (one pipelined IF round)
        const unsigned short* ap = (t & 1) ? ap1 : ap0;
        i32x4 A[16];
        #pragma unroll
        for (int kk = 0; kk < 16; ++kk)
          asm volatile("global_load_dwordx4 %0, %1, off sc0 sc1"
                       : "=v"(A[kk]) : "v"(ap + kk * 32));
        asm volatile("s_waitcnt vmcnt(0)" ::: "memory");
        __builtin_amdgcn_sched_barrier(0);
        #pragma unroll
        for (int kk = 0; kk < 16; ++kk) {
          union { i32x4 i; bf16x8 h; } ua, u0, u1;
          ua.i = A[kk]; u0.i = Bf0[kk]; u1.i = Bf1[kk];
          acc0 = __builtin_amdgcn_mfma_f32_16x16x32_bf16(ua.h, u0.h, acc0, 0, 0, 0);
          acc1 = __builtin_amdgcn_mfma_f32_16x16x32_bf16(ua.h, u1.h, acc1, 0, 0, 0);
        }
      }

      // ---- epilogue: gates -> c,h ; store h direct from registers ----
      unsigned short* nxt = hG + (size_t)((t + 1) & 1) * (BROWS * HDIM);
      #pragma unroll
      for (int reg = 0; reg < 4; ++reg) {
        float gi = acc0[reg];
        float gf = __shfl_xor(acc0[reg], 8, 64);
        float gg = acc1[reg];
        float go = __shfl_xor(acc1[reg], 8, 64);
        float it = sigm(gi), ft = sigm(gf), gt = tanh_f(gg), ot = sigm(go);
        float cn = ft * cst[reg] + it * gt;
        cst[reg] = cn;
        float hn = ot * tanh_f(cn);
        if (lo) {
          int bl = 4 * lg + reg;
          size_t bglob = (size_t)16 * g + bl;
          out[(size_t)t * (BROWS * HDIM) + bglob * HDIM + hcol] = hn;
          if (t + 1 < SLEN) {
            unsigned short hv = f2bf(hn);
            const unsigned short* hp = nxt + bglob * HDIM + hcol;
            asm volatile("global_store_short %0, %1, off sc0 sc1"
                         :: "v"(hp), "v"(hv) : "memory");
          } else {
            out[HS + bglob * HDIM + hcol] = hn;
            out[HS + BROWS * HDIM + bglob * HDIM + hcol] = cn;
          }
        }
      }
      if (t + 1 < SLEN)
        asm volatile("s_waitcnt vmcnt(0)" ::: "memory");  // h stores drained pre-barrier
    } else if (t + 1 < SLEN) {
      PROD(t + 1, (t + 1) & 1);
    }

    if (t + 1 < SLEN) {
      __syncthreads();          // rec stores drained + ring[t+1] written
      if (tid == 0)
        __hip_atomic_store(flags + (size_t)(g * GW + w) * 16, (unsigned)(t + 1),
                           __ATOMIC_RELAXED, __HIP_MEMORY_SCOPE_AGENT);
    }
  }
}

extern "C" void kernel_launch(void* const* d_in, const int* in_sizes, int n_in,
                              void* d_out, int out_size, void* d_ws, size_t ws_size,
                              hipStream_t stream) {
  const float* x    = (const float*)d_in[0];
  const float* W    = (const float*)d_in[1];
  const float* U    = (const float*)d_in[2];
  const float* bias = (const float*)d_in[3];
  float* out = (float*)d_out;

  unsigned short* CT = (unsigned short*)d_ws;                                    // 4 MiB
  unsigned short* hG = (unsigned short*)((char*)d_ws + (size_t)2048 * 1024 * 2); // 128 KiB
  unsigned* flags = (unsigned*)((char*)d_ws + (size_t)2048 * 1024 * 2
                                            + (size_t)2 * BROWS * HDIM * 2);     // 4 KiB

  hipMemsetAsync(flags, 0, NGROUP * GW * 16 * sizeof(unsigned), stream);
  prep_ct<<<1024, 256, 0, stream>>>(W, U, CT);
  lstm_persist<<<NWG, NTHREADS, 0, stream>>>(x, bias, CT, hG, flags, out);
}